// Round 16
// baseline (385.698 us; speedup 1.0000x reference)
//
#include <hip/hip_runtime.h>
#include <math.h>

#define B    32
#define S    2048
#define D    512
#define H    512
#define NP   8
#define NSL  32     // hid-slices per step kernel
#define HSL  16     // hid per slice
#define NBT  8      // batch groups
#define BG   4      // batches per group
#define MAXCH 256   // max total attn chunks (schedule guarantees <= 224+32)

__device__ __forceinline__ float sigmoidf_(float x) {
  return 1.0f / (1.0f + __expf(-x));
}

// ---------------- init: Wt4 transpose, states, num_sent, ns-proportional chunk schedule ----------------
__global__ __launch_bounds__(256)
void k_init(const float* __restrict__ W_ih, const float* __restrict__ W_hh,
            const float* __restrict__ init_h, const float* __restrict__ init_c,
            const float* __restrict__ init_in, const int* __restrict__ ns_raw,
            float4* __restrict__ Wt4, float* __restrict__ hbuf, float* __restrict__ cbuf,
            float* __restrict__ xin0, int* __restrict__ ns,
            int* __restrict__ chunk_tab, int* __restrict__ chunk_base,
            int* __restrict__ nchunkA, int* __restrict__ rpcA, int* __restrict__ ctot_g) {
  __shared__ float tbuf[64][65];
  const int blk = blockIdx.x, tid = threadIdx.x;
  const int jt = blk & 31, kt = blk >> 5;        // 32 j-tiles x 16 k-tiles of 64x64
  const int j0 = jt * 64, k0 = kt * 64;
  const int r0 = tid >> 6, cc = tid & 63;
  for (int rr = r0; rr < 64; rr += 4) {
    int j = j0 + rr, k = k0 + cc;
    tbuf[rr][cc] = (k < 512) ? W_ih[(size_t)j * 512 + k]
                             : W_hh[(size_t)j * 512 + (k - 512)];
  }
  __syncthreads();
  #pragma unroll
  for (int i = 0; i < 4; ++i) {
    const int kk4 = r0 * 4 + i;                  // 0..15
    Wt4[(size_t)(kt * 16 + kk4) * 2048 + j0 + cc] =
        make_float4(tbuf[cc][kk4 * 4 + 0], tbuf[cc][kk4 * 4 + 1],
                    tbuf[cc][kk4 * 4 + 2], tbuf[cc][kk4 * 4 + 3]);
  }

  int idx = blk * 256 + tid;
  if (idx < B * H) {
    int d = idx & 511;
    hbuf[idx] = init_h[d];   // buffer 0
    cbuf[idx] = init_c[d];
    xin0[idx] = init_in[d];
  }
  if (idx == 0) {
    // num_sent >= 1 always. If int64 (LE), high word of elem 0 (raw[1]) is 0.
    bool is64 = (ns_raw[1] == 0);
    int total = 0;
    for (int i2 = 0; i2 < B; ++i2) {
      int v = is64 ? ns_raw[2 * i2] : ns_raw[i2];
      ns[i2] = v; total += v;
    }
    // ns-proportional chunking: ~224 chunks of ~total/224 rows each (<=256 total)
    int cidx = 0;
    for (int b2 = 0; b2 < B; ++b2) {
      int nch = (224 * ns[b2]) / total;
      if (nch < 1) nch = 1;
      int rpc = (ns[b2] + nch - 1) / nch;
      nch = (ns[b2] + rpc - 1) / rpc;            // drop empty tail chunks
      chunk_base[b2] = cidx;
      nchunkA[b2] = nch;
      rpcA[b2] = rpc;
      for (int c = 0; c < nch; ++c) chunk_tab[cidx++] = (b2 << 16) | c;
    }
    ctot_g[0] = cidx;
  }
}

// ---------------- fused step kernel (phase B/C identical to round 15) ----------------
// grid 256 = (sl: 32 hid-slices) x (bg: 8 groups of 4 batches), 512 threads.
__global__ __launch_bounds__(512, 1)
void k_step(const float* __restrict__ xin0, const float* __restrict__ bih,
            const float* __restrict__ bhh, const float* __restrict__ Wq,
            const float* __restrict__ scW, const float* __restrict__ scb,
            const float4* __restrict__ Wt4,
            const float* __restrict__ ch_m, const float* __restrict__ ch_l,
            const float* __restrict__ ch_o,
            const int* __restrict__ chunk_base, const int* __restrict__ nchunkA,
            float* __restrict__ hbuf, float* __restrict__ cbuf,
            float* __restrict__ qpart, float* __restrict__ out, int t) {
  __shared__ float X[BG][1024];       // 16 KB: [xin | h(t-1)] per batch
  __shared__ float gacc[8][64][5];    // 10 KB (pad 5)
  __shared__ float gl[4][16][BG];     // gate values
  __shared__ float hl[BG][16];        // h slice for qpart
  __shared__ float sred[8][BG];       // score partials [wave][b]

  const int tid = threadIdx.x;
  const int sl = blockIdx.x >> 3;     // 0..31
  const int bg = blockIdx.x & 7;      // 0..7
  const int b0 = bg * BG;

  // ---- phase A: combine chunk partials (dynamic schedule) ----
  if (t == 0) {
    #pragma unroll
    for (int bl = 0; bl < BG; ++bl)
      X[bl][tid] = xin0[(b0 + bl) * 512 + tid];
  } else {
    const float swd = scW[tid];
    #pragma unroll
    for (int bl = 0; bl < BG; ++bl) {
      const int b = b0 + bl;
      const int cb = chunk_base[b], nc = nchunkA[b];
      float M = -1e30f;
      for (int c = 0; c < nc; ++c) M = fmaxf(M, ch_m[cb + c]);
      float L = 0.f, v = 0.f;
      for (int c = 0; c < nc; ++c) {
        float e = __expf(ch_m[cb + c] - M);
        L += ch_l[cb + c] * e;
        v += ch_o[((size_t)(cb + c)) * 512 + tid] * e;
      }
      v *= (1.0f / L);
      X[bl][tid] = v;
      float p = v * swd;
      #pragma unroll
      for (int off = 32; off > 0; off >>= 1) p += __shfl_xor(p, off);
      if ((tid & 63) == 0) sred[tid >> 6][bl] = p;
    }
  }
  // copy h(t-1) into X[.][512..1023]: 4 batches x 128 float4 = 512 float4
  if (t < NP) {
    const float4* hsrc = (const float4*)(hbuf + (t & 1) * (B * 512));
    int bl = tid >> 7;
    int off = tid & 127;
    float4 hv = hsrc[(b0 + bl) * 128 + off];
    *(float4*)&X[bl][512 + off * 4] = hv;
  }
  __syncthreads();

  if (t >= 1 && tid < BG) {
    float s = 0.f;
    #pragma unroll
    for (int w = 0; w < 8; ++w) s += sred[w][tid];
    if (sl == 0) out[(t - 1) * B + b0 + tid] = s + scb[0];
  }
  if (t >= NP) return;   // t==8: final-score-only call

  // ---- phase B: gates (Wt4 dwordx4 stream) ----
  {
    const int jloc = tid & 63;              // (gi, ho)
    const int kc = tid >> 6;                // wave id = k-chunk of 128
    const int gi = jloc >> 4, ho = jloc & 15;
    const int jg = gi * 512 + sl * HSL + ho;
    const int k0c = kc * 128;
    const float4* wp4 = Wt4 + (size_t)(kc * 32) * 2048 + jg;
    float acc[BG] = {0, 0, 0, 0};
    for (int kk4 = 0; kk4 < 32; kk4 += 4) {     // 4 wide loads = 16 k per iter
      const float4 w0 = wp4[(size_t)(kk4 + 0) * 2048];
      const float4 w1 = wp4[(size_t)(kk4 + 1) * 2048];
      const float4 w2 = wp4[(size_t)(kk4 + 2) * 2048];
      const float4 w3 = wp4[(size_t)(kk4 + 3) * 2048];
      #pragma unroll
      for (int bl = 0; bl < BG; ++bl) {
        const float4 x0 = *(const float4*)&X[bl][k0c + kk4 * 4];
        const float4 x1 = *(const float4*)&X[bl][k0c + kk4 * 4 + 4];
        const float4 x2 = *(const float4*)&X[bl][k0c + kk4 * 4 + 8];
        const float4 x3 = *(const float4*)&X[bl][k0c + kk4 * 4 + 12];
        acc[bl] += w0.x * x0.x + w0.y * x0.y + w0.z * x0.z + w0.w * x0.w
                 + w1.x * x1.x + w1.y * x1.y + w1.z * x1.z + w1.w * x1.w
                 + w2.x * x2.x + w2.y * x2.y + w2.z * x2.z + w2.w * x2.w
                 + w3.x * x3.x + w3.y * x3.y + w3.z * x3.z + w3.w * x3.w;
      }
    }
    #pragma unroll
    for (int bl = 0; bl < BG; ++bl) gacc[kc][jloc][bl] = acc[bl];
  }
  __syncthreads();

  // ---- kc-reduce + bias -> gl (256 threads: 4 bl x 64 jloc) ----
  if (tid < 256) {
    const int bl = tid >> 6, jloc = tid & 63;
    const int gi = jloc >> 4, ho = jloc & 15;
    const int jg = gi * 512 + sl * HSL + ho;
    float g = bih[jg] + bhh[jg];
    #pragma unroll
    for (int kc = 0; kc < 8; ++kc) g += gacc[kc][jloc][bl];
    gl[gi][ho][bl] = g;
  }
  __syncthreads();

  // ---- LSTM cell (64 threads: 4 bl x 16 ho) ----
  if (tid < BG * HSL) {
    const int ho = tid & 15, bl = tid >> 4;
    const int bglob = b0 + bl, hid = sl * HSL + ho;
    float i_ = sigmoidf_(gl[0][ho][bl]);
    float f_ = sigmoidf_(gl[1][ho][bl]);
    float g_ = tanhf(gl[2][ho][bl]);
    float o_ = sigmoidf_(gl[3][ho][bl]);
    float cv = cbuf[bglob * 512 + hid];          // unique owner (sl,bg)
    float cn = f_ * cv + i_ * g_;
    cbuf[bglob * 512 + hid] = cn;
    float hv = o_ * tanhf(cn);
    hbuf[((t + 1) & 1) * (B * 512) + bglob * 512 + hid] = hv;
    hl[bl][ho] = hv;
  }
  __syncthreads();

  // ---- q-partials: qpart[sl][b][d] = sum_{ho} h[b][sl*16+ho] * Wq[sl*16+ho][d] ----
  {
    float w[HSL];
    #pragma unroll
    for (int ho = 0; ho < HSL; ++ho)
      w[ho] = Wq[(size_t)(sl * HSL + ho) * 512 + tid];
    #pragma unroll
    for (int bl = 0; bl < BG; ++bl) {
      float acc = 0.f;
      #pragma unroll
      for (int ho = 0; ho < HSL; ++ho) acc += hl[bl][ho] * w[ho];
      qpart[((size_t)sl * B + b0 + bl) * 512 + tid] = acc;
    }
  }
}

// ---------------- attn: load-balanced chunks (R11 inner loop) ----------------
// grid 256 blocks x 512 threads = 8 waves. Block j processes chunks j, j+256,...
// Per chunk: re-sum q for the chunk's batch, pairwise-row online softmax over
// [c*rpc, min((c+1)*rpc, ns)), write partials to slot ci.
__global__ __launch_bounds__(512, 1)
void k_attn(const float* __restrict__ enc, const float* __restrict__ qpart,
            const int* __restrict__ ns_buf, const int* __restrict__ chunk_tab,
            const int* __restrict__ rpcA, const int* __restrict__ ctot_g,
            float* __restrict__ ch_m, float* __restrict__ ch_l,
            float* __restrict__ ch_o) {
  __shared__ float q_lds[512];
  __shared__ float wm[8], wl[8];
  __shared__ float wo[8][512];
  const int tid = threadIdx.x;
  const int lane = tid & 63;
  const int wv = tid >> 6;
  const int ctot = ctot_g[0];

  for (int ci = blockIdx.x; ci < ctot; ci += 256) {
    const int ent = chunk_tab[ci];
    const int b = ent >> 16, c = ent & 0xffff;
    const int rpc = rpcA[b];
    const int s0 = c * rpc;
    const int send = min(s0 + rpc, ns_buf[b]);

    __syncthreads();   // protect LDS from previous chunk's readers

    // q = sum over 32 slices for this chunk's batch
    {
      float s = 0.f;
      #pragma unroll 8
      for (int sl = 0; sl < NSL; ++sl)
        s += qpart[((size_t)sl * B + b) * 512 + tid];
      q_lds[tid] = s;
    }
    __syncthreads();

    const float4 qa  = *(const float4*)&q_lds[lane * 8];
    const float4 qb4 = *(const float4*)&q_lds[lane * 8 + 4];

    float m = -1e30f, l = 0.f;
    float o0=0,o1=0,o2=0,o3=0,o4=0,o5=0,o6=0,o7=0;
    const size_t rowbase = (size_t)b * S;

    int r = s0 + 2 * wv;
    if (r < send) {
      bool has1 = (r + 1 < send);
      const float4* p0 = (const float4*)(enc + (rowbase + r) * 512 + lane * 8);
      const float4* p1 = (const float4*)(enc + (rowbase + (has1 ? r + 1 : r)) * 512 + lane * 8);
      float4 a0 = p0[0], a1 = p0[1];
      float4 c0 = p1[0], c1 = p1[1];
      while (true) {
        const int rn = r + 16;
        const bool hasn = (rn < send);
        float4 na0, na1, nc0, nc1;
        bool nhas1 = false;
        if (hasn) {
          nhas1 = (rn + 1 < send);
          const float4* f0 = (const float4*)(enc + (rowbase + rn) * 512 + lane * 8);
          const float4* f1 = (const float4*)(enc + (rowbase + (nhas1 ? rn + 1 : rn)) * 512 + lane * 8);
          na0 = f0[0]; na1 = f0[1]; nc0 = f1[0]; nc1 = f1[1];
        }
        float d0 = qa.x*a0.x + qa.y*a0.y + qa.z*a0.z + qa.w*a0.w
                 + qb4.x*a1.x + qb4.y*a1.y + qb4.z*a1.z + qb4.w*a1.w;
        float d1 = qa.x*c0.x + qa.y*c0.y + qa.z*c0.z + qa.w*c0.w
                 + qb4.x*c1.x + qb4.y*c1.y + qb4.z*c1.z + qb4.w*c1.w;
        #pragma unroll
        for (int off = 32; off > 0; off >>= 1) {
          d0 += __shfl_xor(d0, off);
          d1 += __shfl_xor(d1, off);
        }
        if (!has1) d1 = -1e30f;            // wave-uniform
        float nm = fmaxf(m, fmaxf(d0, d1));
        float sc = __expf(m - nm);
        float w0 = __expf(d0 - nm);
        float w1 = __expf(d1 - nm);        // 0 when pair's 2nd row invalid
        l = l * sc + w0 + w1;
        o0 = o0*sc + w0*a0.x + w1*c0.x; o1 = o1*sc + w0*a0.y + w1*c0.y;
        o2 = o2*sc + w0*a0.z + w1*c0.z; o3 = o3*sc + w0*a0.w + w1*c0.w;
        o4 = o4*sc + w0*a1.x + w1*c1.x; o5 = o5*sc + w0*a1.y + w1*c1.y;
        o6 = o6*sc + w0*a1.z + w1*c1.z; o7 = o7*sc + w0*a1.w + w1*c1.w;
        m = nm;
        if (!hasn) break;
        r = rn; has1 = nhas1;
        a0 = na0; a1 = na1; c0 = nc0; c1 = nc1;
      }
    }
    if (lane == 0) { wm[wv] = m; wl[wv] = l; }
    float4* wop = (float4*)&wo[wv][lane * 8];
    wop[0] = make_float4(o0, o1, o2, o3);
    wop[1] = make_float4(o4, o5, o6, o7);
    __syncthreads();

    float M = wm[0];
    #pragma unroll
    for (int w = 1; w < 8; ++w) M = fmaxf(M, wm[w]);
    float e[8]; float L = 0.f;
    #pragma unroll
    for (int w = 0; w < 8; ++w) { e[w] = __expf(wm[w] - M); L += wl[w] * e[w]; }
    if (tid == 0) { ch_m[ci] = M; ch_l[ci] = L; }
    float v = 0.f;
    #pragma unroll
    for (int w = 0; w < 8; ++w) v += wo[w][tid] * e[w];
    ch_o[((size_t)ci) * 512 + tid] = v;
  }
}

extern "C" void kernel_launch(void* const* d_in, const int* in_sizes, int n_in,
                              void* d_out, int out_size, void* d_ws, size_t ws_size,
                              hipStream_t stream) {
  const float* enc     = (const float*)d_in[0];
  const int*   ns_raw  = (const int*)d_in[1];
  // d_in[2] = num_pred (8)
  const float* init_h  = (const float*)d_in[3];
  const float* init_c  = (const float*)d_in[4];
  const float* init_in = (const float*)d_in[5];
  const float* W_ih    = (const float*)d_in[6];
  const float* W_hh    = (const float*)d_in[7];
  const float* b_ih    = (const float*)d_in[8];
  const float* b_hh    = (const float*)d_in[9];
  const float* Wq      = (const float*)d_in[10];
  const float* score_W = (const float*)d_in[11];
  const float* score_b = (const float*)d_in[12];
  float* out = (float*)d_out;

  float* ws    = (float*)d_ws;
  float4* Wt4  = (float4*)ws;            // 2097152 floats
  float* hbuf  = ws + 2097152;           // 32768 (double-buffered)
  float* cbuf  = ws + 2129920;           // 16384
  float* xin0  = ws + 2146304;           // 16384
  float* qpart = ws + 2162688;           // 524288
  float* ch_m  = ws + 2686976;           // MAXCH = 256
  float* ch_l  = ws + 2687232;           // 256
  float* ch_o  = ws + 2687488;           // MAXCH*512 = 131072
  int*   ns         = (int*)(ws + 2818560);  // 32
  int*   chunk_tab  = (int*)(ws + 2818592);  // 256
  int*   chunk_base = (int*)(ws + 2818848);  // 32
  int*   nchunkA    = (int*)(ws + 2818880);  // 32
  int*   rpcA       = (int*)(ws + 2818912);  // 32
  int*   ctot_g     = (int*)(ws + 2818944);  // 1

  k_init<<<512, 256, 0, stream>>>(W_ih, W_hh, init_h, init_c, init_in, ns_raw,
                                  Wt4, hbuf, cbuf, xin0, ns,
                                  chunk_tab, chunk_base, nchunkA, rpcA, ctot_g);
  for (int t = 0; t < NP; ++t) {
    k_step<<<NSL * NBT, 512, 0, stream>>>(xin0, b_ih, b_hh, Wq, score_W, score_b, Wt4,
                                          ch_m, ch_l, ch_o, chunk_base, nchunkA,
                                          hbuf, cbuf, qpart, out, t);
    k_attn<<<256, 512, 0, stream>>>(enc, qpart, ns, chunk_tab, rpcA, ctot_g,
                                    ch_m, ch_l, ch_o);
  }
  k_step<<<NSL * NBT, 512, 0, stream>>>(xin0, b_ih, b_hh, Wq, score_W, score_b, Wt4,
                                        ch_m, ch_l, ch_o, chunk_base, nchunkA,
                                        hbuf, cbuf, qpart, out, NP);
}

// Round 17
// 374.543 us; speedup vs baseline: 1.0298x; 1.0298x over previous
//
#include <hip/hip_runtime.h>
#include <math.h>

#define B    32
#define S    2048
#define D    512
#define H    512
#define NP   8
#define NSL  32     // hid-slices per step kernel
#define HSL  16     // hid per slice
#define NBT  8      // batch groups
#define BG   4      // batches per group
#define SLOTS 16    // fixed attn partial slots per batch (static phase A)

__device__ __forceinline__ float sigmoidf_(float x) {
  return 1.0f / (1.0f + __expf(-x));
}

// ---------------- init: Wt4 transpose, states, slot buffers, ns-proportional schedule ----------------
__global__ __launch_bounds__(256)
void k_init(const float* __restrict__ W_ih, const float* __restrict__ W_hh,
            const float* __restrict__ init_h, const float* __restrict__ init_c,
            const float* __restrict__ init_in, const int* __restrict__ ns_raw,
            float4* __restrict__ Wt4, float* __restrict__ hbuf, float* __restrict__ cbuf,
            float* __restrict__ xin0, int* __restrict__ ns,
            float* __restrict__ ch_m, float* __restrict__ ch_l, float* __restrict__ ch_o,
            int* __restrict__ chunk_bc, int* __restrict__ chunk_rows,
            int* __restrict__ ctot_g) {
  __shared__ float tbuf[64][65];
  const int blk = blockIdx.x, tid = threadIdx.x;
  const int jt = blk & 31, kt = blk >> 5;        // 32 j-tiles x 16 k-tiles of 64x64
  const int j0 = jt * 64, k0 = kt * 64;
  const int r0 = tid >> 6, cc = tid & 63;
  for (int rr = r0; rr < 64; rr += 4) {
    int j = j0 + rr, k = k0 + cc;
    tbuf[rr][cc] = (k < 512) ? W_ih[(size_t)j * 512 + k]
                             : W_hh[(size_t)j * 512 + (k - 512)];
  }
  __syncthreads();
  #pragma unroll
  for (int i = 0; i < 4; ++i) {
    const int kk4 = r0 * 4 + i;                  // 0..15
    Wt4[(size_t)(kt * 16 + kk4) * 2048 + j0 + cc] =
        make_float4(tbuf[cc][kk4 * 4 + 0], tbuf[cc][kk4 * 4 + 1],
                    tbuf[cc][kk4 * 4 + 2], tbuf[cc][kk4 * 4 + 3]);
  }

  int idx = blk * 256 + tid;                     // 0 .. 131071
  if (idx < B * H) {
    int d = idx & 511;
    hbuf[idx] = init_h[d];   // buffer 0
    cbuf[idx] = init_c[d];
    xin0[idx] = init_in[d];
  }
  // zero slot buffers (unused slots must stay inert forever)
  ch_o[idx] = 0.f;
  ch_o[idx + 131072] = 0.f;
  if (idx < B * SLOTS) { ch_m[idx] = -1e30f; ch_l[idx] = 0.f; }

  if (idx == 0) {
    // num_sent >= 1 always. If int64 (LE), high word of elem 0 (raw[1]) is 0.
    bool is64 = (ns_raw[1] == 0);
    int total = 0;
    for (int i2 = 0; i2 < B; ++i2) {
      int v = is64 ? ns_raw[2 * i2] : ns_raw[i2];
      ns[i2] = v; total += v;
    }
    // ns-proportional chunks: target ~224 total, 1..16 per batch -> ctot <= 256
    int cidx = 0;
    for (int b2 = 0; b2 < B; ++b2) {
      int nch = (224 * ns[b2]) / total;
      if (nch < 1) nch = 1;
      if (nch > SLOTS) nch = SLOTS;
      int rpc = (ns[b2] + nch - 1) / nch;
      nch = (ns[b2] + rpc - 1) / rpc;            // drop empty tail chunks
      for (int c = 0; c < nch; ++c) {
        int s0 = c * rpc;
        int send = s0 + rpc;
        if (send > ns[b2]) send = ns[b2];
        chunk_bc[cidx]   = (b2 << 8) | c;
        chunk_rows[cidx] = (s0 << 16) | send;
        ++cidx;
      }
    }
    ctot_g[0] = cidx;
  }
}

// ---------------- fused step kernel (phase B/C/D identical to round 15) ----------------
// grid 256 = (sl: 32 hid-slices) x (bg: 8 groups of 4 batches), 512 threads.
// Phase A: STATIC 16-slot combine per batch with uniform guard on unused slots.
__global__ __launch_bounds__(512, 1)
void k_step(const float* __restrict__ xin0, const float* __restrict__ bih,
            const float* __restrict__ bhh, const float* __restrict__ Wq,
            const float* __restrict__ scW, const float* __restrict__ scb,
            const float4* __restrict__ Wt4,
            const float* __restrict__ ch_m, const float* __restrict__ ch_l,
            const float* __restrict__ ch_o,
            float* __restrict__ hbuf, float* __restrict__ cbuf,
            float* __restrict__ qpart, float* __restrict__ out, int t) {
  __shared__ float X[BG][1024];       // 16 KB: [xin | h(t-1)] per batch
  __shared__ float gacc[8][64][5];    // 10 KB (pad 5)
  __shared__ float gl[4][16][BG];     // gate values
  __shared__ float hl[BG][16];        // h slice for qpart
  __shared__ float sred[8][BG];       // score partials [wave][b]

  const int tid = threadIdx.x;
  const int sl = blockIdx.x >> 3;     // 0..31
  const int bg = blockIdx.x & 7;      // 0..7
  const int b0 = bg * BG;

  // ---- phase A ----
  if (t == 0) {
    #pragma unroll
    for (int bl = 0; bl < BG; ++bl)
      X[bl][tid] = xin0[(b0 + bl) * 512 + tid];
  } else {
    const float swd = scW[tid];
    #pragma unroll
    for (int bl = 0; bl < BG; ++bl) {
      const int b = b0 + bl;
      const int cb = b * SLOTS;
      float cm[SLOTS];
      #pragma unroll
      for (int c = 0; c < SLOTS; ++c) cm[c] = ch_m[cb + c];
      float M = -1e30f;
      #pragma unroll
      for (int c = 0; c < SLOTS; ++c) M = fmaxf(M, cm[c]);
      float L = 0.f, v = 0.f;
      #pragma unroll
      for (int c = 0; c < SLOTS; ++c) {
        if (cm[c] > -5e29f) {                      // uniform branch; skip unused
          float e = __expf(cm[c] - M);
          L += ch_l[cb + c] * e;
          v += ch_o[((size_t)(cb + c)) * 512 + tid] * e;
        }
      }
      v *= (1.0f / L);
      X[bl][tid] = v;
      float p = v * swd;
      #pragma unroll
      for (int off = 32; off > 0; off >>= 1) p += __shfl_xor(p, off);
      if ((tid & 63) == 0) sred[tid >> 6][bl] = p;
    }
  }
  // copy h(t-1) into X[.][512..1023]: 4 batches x 128 float4 = 512 float4
  if (t < NP) {
    const float4* hsrc = (const float4*)(hbuf + (t & 1) * (B * 512));
    int bl = tid >> 7;
    int off = tid & 127;
    float4 hv = hsrc[(b0 + bl) * 128 + off];
    *(float4*)&X[bl][512 + off * 4] = hv;
  }
  __syncthreads();

  if (t >= 1 && tid < BG) {
    float s = 0.f;
    #pragma unroll
    for (int w = 0; w < 8; ++w) s += sred[w][tid];
    if (sl == 0) out[(t - 1) * B + b0 + tid] = s + scb[0];
  }
  if (t >= NP) return;   // t==8: final-score-only call

  // ---- phase B: gates (Wt4 dwordx4 stream) ----
  {
    const int jloc = tid & 63;              // (gi, ho)
    const int kc = tid >> 6;                // wave id = k-chunk of 128
    const int gi = jloc >> 4, ho = jloc & 15;
    const int jg = gi * 512 + sl * HSL + ho;
    const int k0c = kc * 128;
    const float4* wp4 = Wt4 + (size_t)(kc * 32) * 2048 + jg;
    float acc[BG] = {0, 0, 0, 0};
    for (int kk4 = 0; kk4 < 32; kk4 += 4) {     // 4 wide loads = 16 k per iter
      const float4 w0 = wp4[(size_t)(kk4 + 0) * 2048];
      const float4 w1 = wp4[(size_t)(kk4 + 1) * 2048];
      const float4 w2 = wp4[(size_t)(kk4 + 2) * 2048];
      const float4 w3 = wp4[(size_t)(kk4 + 3) * 2048];
      #pragma unroll
      for (int bl = 0; bl < BG; ++bl) {
        const float4 x0 = *(const float4*)&X[bl][k0c + kk4 * 4];
        const float4 x1 = *(const float4*)&X[bl][k0c + kk4 * 4 + 4];
        const float4 x2 = *(const float4*)&X[bl][k0c + kk4 * 4 + 8];
        const float4 x3 = *(const float4*)&X[bl][k0c + kk4 * 4 + 12];
        acc[bl] += w0.x * x0.x + w0.y * x0.y + w0.z * x0.z + w0.w * x0.w
                 + w1.x * x1.x + w1.y * x1.y + w1.z * x1.z + w1.w * x1.w
                 + w2.x * x2.x + w2.y * x2.y + w2.z * x2.z + w2.w * x2.w
                 + w3.x * x3.x + w3.y * x3.y + w3.z * x3.z + w3.w * x3.w;
      }
    }
    #pragma unroll
    for (int bl = 0; bl < BG; ++bl) gacc[kc][jloc][bl] = acc[bl];
  }
  __syncthreads();

  // ---- kc-reduce + bias -> gl (256 threads: 4 bl x 64 jloc) ----
  if (tid < 256) {
    const int bl = tid >> 6, jloc = tid & 63;
    const int gi = jloc >> 4, ho = jloc & 15;
    const int jg = gi * 512 + sl * HSL + ho;
    float g = bih[jg] + bhh[jg];
    #pragma unroll
    for (int kc = 0; kc < 8; ++kc) g += gacc[kc][jloc][bl];
    gl[gi][ho][bl] = g;
  }
  __syncthreads();

  // ---- LSTM cell (64 threads: 4 bl x 16 ho) ----
  if (tid < BG * HSL) {
    const int ho = tid & 15, bl = tid >> 4;
    const int bglob = b0 + bl, hid = sl * HSL + ho;
    float i_ = sigmoidf_(gl[0][ho][bl]);
    float f_ = sigmoidf_(gl[1][ho][bl]);
    float g_ = tanhf(gl[2][ho][bl]);
    float o_ = sigmoidf_(gl[3][ho][bl]);
    float cv = cbuf[bglob * 512 + hid];          // unique owner (sl,bg)
    float cn = f_ * cv + i_ * g_;
    cbuf[bglob * 512 + hid] = cn;
    float hv = o_ * tanhf(cn);
    hbuf[((t + 1) & 1) * (B * 512) + bglob * 512 + hid] = hv;
    hl[bl][ho] = hv;
  }
  __syncthreads();

  // ---- q-partials: qpart[sl][b][d] = sum_{ho} h[b][sl*16+ho] * Wq[sl*16+ho][d] ----
  {
    float w[HSL];
    #pragma unroll
    for (int ho = 0; ho < HSL; ++ho)
      w[ho] = Wq[(size_t)(sl * HSL + ho) * 512 + tid];
    #pragma unroll
    for (int bl = 0; bl < BG; ++bl) {
      float acc = 0.f;
      #pragma unroll
      for (int ho = 0; ho < HSL; ++ho) acc += hl[bl][ho] * w[ho];
      qpart[((size_t)sl * B + b0 + bl) * 512 + tid] = acc;
    }
  }
}

// ---------------- attn: balanced chunks from table (R11 inner loop) ----------------
// grid 256 x 512 = 8 waves; block j handles table entries j, j+256, ...
__global__ __launch_bounds__(512, 1)
void k_attn(const float* __restrict__ enc, const float* __restrict__ qpart,
            const int* __restrict__ chunk_bc, const int* __restrict__ chunk_rows,
            const int* __restrict__ ctot_g,
            float* __restrict__ ch_m, float* __restrict__ ch_l,
            float* __restrict__ ch_o) {
  __shared__ float q_lds[512];
  __shared__ float wm[8], wl[8];
  __shared__ float wo[8][512];
  const int tid = threadIdx.x;
  const int lane = tid & 63;
  const int wv = tid >> 6;
  const int ctot = ctot_g[0];

  for (int ci = blockIdx.x; ci < ctot; ci += 256) {
    const int bc = chunk_bc[ci];
    const int b = bc >> 8, c = bc & 255;
    const int rows = chunk_rows[ci];
    const int s0 = rows >> 16, send = rows & 0xffff;
    const int slot = b * SLOTS + c;

    __syncthreads();   // protect LDS from previous chunk's readers

    // q = sum over 32 slices for this chunk's batch
    {
      float s = 0.f;
      #pragma unroll 8
      for (int sl = 0; sl < NSL; ++sl)
        s += qpart[((size_t)sl * B + b) * 512 + tid];
      q_lds[tid] = s;
    }
    __syncthreads();

    const float4 qa  = *(const float4*)&q_lds[lane * 8];
    const float4 qb4 = *(const float4*)&q_lds[lane * 8 + 4];

    float m = -1e30f, l = 0.f;
    float o0=0,o1=0,o2=0,o3=0,o4=0,o5=0,o6=0,o7=0;
    const size_t rowbase = (size_t)b * S;

    int r = s0 + 2 * wv;
    if (r < send) {
      bool has1 = (r + 1 < send);
      const float4* p0 = (const float4*)(enc + (rowbase + r) * 512 + lane * 8);
      const float4* p1 = (const float4*)(enc + (rowbase + (has1 ? r + 1 : r)) * 512 + lane * 8);
      float4 a0 = p0[0], a1 = p0[1];
      float4 c0 = p1[0], c1 = p1[1];
      while (true) {
        const int rn = r + 16;
        const bool hasn = (rn < send);
        float4 na0, na1, nc0, nc1;
        bool nhas1 = false;
        if (hasn) {
          nhas1 = (rn + 1 < send);
          const float4* f0 = (const float4*)(enc + (rowbase + rn) * 512 + lane * 8);
          const float4* f1 = (const float4*)(enc + (rowbase + (nhas1 ? rn + 1 : rn)) * 512 + lane * 8);
          na0 = f0[0]; na1 = f0[1]; nc0 = f1[0]; nc1 = f1[1];
        }
        float d0 = qa.x*a0.x + qa.y*a0.y + qa.z*a0.z + qa.w*a0.w
                 + qb4.x*a1.x + qb4.y*a1.y + qb4.z*a1.z + qb4.w*a1.w;
        float d1 = qa.x*c0.x + qa.y*c0.y + qa.z*c0.z + qa.w*c0.w
                 + qb4.x*c1.x + qb4.y*c1.y + qb4.z*c1.z + qb4.w*c1.w;
        #pragma unroll
        for (int off = 32; off > 0; off >>= 1) {
          d0 += __shfl_xor(d0, off);
          d1 += __shfl_xor(d1, off);
        }
        if (!has1) d1 = -1e30f;            // wave-uniform
        float nm = fmaxf(m, fmaxf(d0, d1));
        float sc = __expf(m - nm);
        float w0 = __expf(d0 - nm);
        float w1 = __expf(d1 - nm);        // 0 when pair's 2nd row invalid
        l = l * sc + w0 + w1;
        o0 = o0*sc + w0*a0.x + w1*c0.x; o1 = o1*sc + w0*a0.y + w1*c0.y;
        o2 = o2*sc + w0*a0.z + w1*c0.z; o3 = o3*sc + w0*a0.w + w1*c0.w;
        o4 = o4*sc + w0*a1.x + w1*c1.x; o5 = o5*sc + w0*a1.y + w1*c1.y;
        o6 = o6*sc + w0*a1.z + w1*c1.z; o7 = o7*sc + w0*a1.w + w1*c1.w;
        m = nm;
        if (!hasn) break;
        r = rn; has1 = nhas1;
        a0 = na0; a1 = na1; c0 = nc0; c1 = nc1;
      }
    }
    if (lane == 0) { wm[wv] = m; wl[wv] = l; }
    float4* wop = (float4*)&wo[wv][lane * 8];
    wop[0] = make_float4(o0, o1, o2, o3);
    wop[1] = make_float4(o4, o5, o6, o7);
    __syncthreads();

    float M = wm[0];
    #pragma unroll
    for (int w = 1; w < 8; ++w) M = fmaxf(M, wm[w]);
    float e[8]; float L = 0.f;
    #pragma unroll
    for (int w = 0; w < 8; ++w) { e[w] = __expf(wm[w] - M); L += wl[w] * e[w]; }
    if (tid == 0) { ch_m[slot] = M; ch_l[slot] = L; }
    float v = 0.f;
    #pragma unroll
    for (int w = 0; w < 8; ++w) v += wo[w][tid] * e[w];
    ch_o[((size_t)slot) * 512 + tid] = v;
  }
}

extern "C" void kernel_launch(void* const* d_in, const int* in_sizes, int n_in,
                              void* d_out, int out_size, void* d_ws, size_t ws_size,
                              hipStream_t stream) {
  const float* enc     = (const float*)d_in[0];
  const int*   ns_raw  = (const int*)d_in[1];
  // d_in[2] = num_pred (8)
  const float* init_h  = (const float*)d_in[3];
  const float* init_c  = (const float*)d_in[4];
  const float* init_in = (const float*)d_in[5];
  const float* W_ih    = (const float*)d_in[6];
  const float* W_hh    = (const float*)d_in[7];
  const float* b_ih    = (const float*)d_in[8];
  const float* b_hh    = (const float*)d_in[9];
  const float* Wq      = (const float*)d_in[10];
  const float* score_W = (const float*)d_in[11];
  const float* score_b = (const float*)d_in[12];
  float* out = (float*)d_out;

  float* ws    = (float*)d_ws;
  float4* Wt4  = (float4*)ws;              // 2097152 floats
  float* hbuf  = ws + 2097152;             // 32768 (double-buffered)
  float* cbuf  = ws + 2129920;             // 16384
  float* xin0  = ws + 2146304;             // 16384
  float* qpart = ws + 2162688;             // 524288
  float* ch_m  = ws + 2686976;             // B*SLOTS = 512
  float* ch_l  = ws + 2687488;             // 512
  float* ch_o  = ws + 2688000;             // B*SLOTS*512 = 262144
  int*   ns         = (int*)(ws + 2950144);  // 32
  int*   chunk_bc   = (int*)(ws + 2950176);  // 256
  int*   chunk_rows = (int*)(ws + 2950432);  // 256
  int*   ctot_g     = (int*)(ws + 2950688);  // 1

  k_init<<<512, 256, 0, stream>>>(W_ih, W_hh, init_h, init_c, init_in, ns_raw,
                                  Wt4, hbuf, cbuf, xin0, ns,
                                  ch_m, ch_l, ch_o, chunk_bc, chunk_rows, ctot_g);
  for (int t = 0; t < NP; ++t) {
    k_step<<<NSL * NBT, 512, 0, stream>>>(xin0, b_ih, b_hh, Wq, score_W, score_b, Wt4,
                                          ch_m, ch_l, ch_o,
                                          hbuf, cbuf, qpart, out, t);
    k_attn<<<256, 512, 0, stream>>>(enc, qpart, chunk_bc, chunk_rows, ctot_g,
                                    ch_m, ch_l, ch_o);
  }
  k_step<<<NSL * NBT, 512, 0, stream>>>(xin0, b_ih, b_hh, Wq, score_W, score_b, Wt4,
                                        ch_m, ch_l, ch_o,
                                        hbuf, cbuf, qpart, out, NP);
}

// Round 18
// 286.333 us; speedup vs baseline: 1.3470x; 1.3081x over previous
//
#include <hip/hip_runtime.h>
#include <math.h>

#define B    32
#define S    2048
#define D    512
#define H    512
#define NP   8
#define NSL  32     // hid-slices per step kernel
#define HSL  16     // hid per slice
#define NBT  8      // batch groups
#define BG   4      // batches per group
#define NCH  8      // attn chunks per batch
#define SCHUNK 256

__device__ __forceinline__ float sigmoidf_(float x) {
  return 1.0f / (1.0f + __expf(-x));
}

// ---------------- init: Wt4[k4][j] = float4{Wcat[j][4k4..4k4+3]}, states, num_sent ----------------
// Wcat = [W_ih | W_hh] rows j (0..2047), concat-k (0..1023). LDS-tiled transpose.
__global__ __launch_bounds__(256)
void k_init(const float* __restrict__ W_ih, const float* __restrict__ W_hh,
            const float* __restrict__ init_h, const float* __restrict__ init_c,
            const float* __restrict__ init_in, const int* __restrict__ ns_raw,
            float4* __restrict__ Wt4, float* __restrict__ hbuf, float* __restrict__ cbuf,
            float* __restrict__ xin0, int* __restrict__ ns) {
  __shared__ float tbuf[64][65];
  const int blk = blockIdx.x, tid = threadIdx.x;
  const int jt = blk & 31, kt = blk >> 5;        // 32 j-tiles x 16 k-tiles of 64x64
  const int j0 = jt * 64, k0 = kt * 64;
  const int r0 = tid >> 6, cc = tid & 63;
  for (int rr = r0; rr < 64; rr += 4) {
    int j = j0 + rr, k = k0 + cc;
    tbuf[rr][cc] = (k < 512) ? W_ih[(size_t)j * 512 + k]
                             : W_hh[(size_t)j * 512 + (k - 512)];
  }
  __syncthreads();
  // 16 k4-rows per tile; 4 r-groups x 4 each. Write coalesced along j (lane=cc).
  #pragma unroll
  for (int i = 0; i < 4; ++i) {
    const int kk4 = r0 * 4 + i;                  // 0..15
    Wt4[(size_t)(kt * 16 + kk4) * 2048 + j0 + cc] =
        make_float4(tbuf[cc][kk4 * 4 + 0], tbuf[cc][kk4 * 4 + 1],
                    tbuf[cc][kk4 * 4 + 2], tbuf[cc][kk4 * 4 + 3]);
  }

  int idx = blk * 256 + tid;
  if (idx < B * H) {
    int d = idx & 511;
    hbuf[idx] = init_h[d];   // buffer 0
    cbuf[idx] = init_c[d];
    xin0[idx] = init_in[d];
  }
  if (idx == 0) {
    // num_sent >= 1 always. If int64 (LE), high word of elem 0 (raw[1]) is 0.
    bool is64 = (ns_raw[1] == 0);
    for (int i2 = 0; i2 < B; ++i2) ns[i2] = is64 ? ns_raw[2 * i2] : ns_raw[i2];
  }
}

// ---------------- fused step kernel ----------------
// grid 256 = (sl: 32 hid-slices) x (bg: 8 groups of 4 batches), 512 threads.
// Phase B streams Wt4 as dwordx4 (4x fewer load instrs, 4 wide loads in
// flight per wave) -- attacks the latency-exposed weight stream.
__global__ __launch_bounds__(512, 1)
void k_step(const float* __restrict__ xin0, const float* __restrict__ bih,
            const float* __restrict__ bhh, const float* __restrict__ Wq,
            const float* __restrict__ scW, const float* __restrict__ scb,
            const float4* __restrict__ Wt4,
            const float* __restrict__ ch_m, const float* __restrict__ ch_l,
            const float* __restrict__ ch_o,
            float* __restrict__ hbuf, float* __restrict__ cbuf,
            float* __restrict__ qpart, float* __restrict__ out, int t) {
  __shared__ float X[BG][1024];       // 16 KB: [xin | h(t-1)] per batch
  __shared__ float gacc[8][64][5];    // 10 KB (pad 5)
  __shared__ float gl[4][16][BG];     // gate values
  __shared__ float hl[BG][16];        // h slice for qpart
  __shared__ float sred[8][BG];       // score partials [wave][b]

  const int tid = threadIdx.x;
  const int sl = blockIdx.x >> 3;     // 0..31
  const int bg = blockIdx.x & 7;      // 0..7
  const int b0 = bg * BG;

  // ---- phase A ----
  if (t == 0) {
    #pragma unroll
    for (int bl = 0; bl < BG; ++bl)
      X[bl][tid] = xin0[(b0 + bl) * 512 + tid];
  } else {
    const float swd = scW[tid];
    #pragma unroll
    for (int bl = 0; bl < BG; ++bl) {
      const int b = b0 + bl;
      float M = -1e30f;
      #pragma unroll
      for (int c = 0; c < NCH; ++c) M = fmaxf(M, ch_m[b * NCH + c]);
      float e[NCH]; float L = 0.f;
      #pragma unroll
      for (int c = 0; c < NCH; ++c) {
        e[c] = __expf(ch_m[b * NCH + c] - M);
        L += ch_l[b * NCH + c] * e[c];
      }
      float v = 0.f;
      #pragma unroll
      for (int c = 0; c < NCH; ++c)
        v += ch_o[((size_t)(b * NCH + c)) * 512 + tid] * e[c];
      v *= (1.0f / L);
      X[bl][tid] = v;
      float p = v * swd;
      #pragma unroll
      for (int off = 32; off > 0; off >>= 1) p += __shfl_xor(p, off);
      if ((tid & 63) == 0) sred[tid >> 6][bl] = p;
    }
  }
  // copy h(t-1) into X[.][512..1023]: 4 batches x 128 float4 = 512 float4
  if (t < NP) {
    const float4* hsrc = (const float4*)(hbuf + (t & 1) * (B * 512));
    int bl = tid >> 7;
    int off = tid & 127;
    float4 hv = hsrc[(b0 + bl) * 128 + off];
    *(float4*)&X[bl][512 + off * 4] = hv;
  }
  __syncthreads();

  if (t >= 1 && tid < BG) {
    float s = 0.f;
    #pragma unroll
    for (int w = 0; w < 8; ++w) s += sred[w][tid];
    if (sl == 0) out[(t - 1) * B + b0 + tid] = s + scb[0];
  }
  if (t >= NP) return;   // t==8: final-score-only call

  // ---- phase B: gates (Wt4 dwordx4 stream) ----
  {
    const int jloc = tid & 63;              // (gi, ho)
    const int kc = tid >> 6;                // wave id = k-chunk of 128
    const int gi = jloc >> 4, ho = jloc & 15;
    const int jg = gi * 512 + sl * HSL + ho;
    const int k0c = kc * 128;
    const float4* wp4 = Wt4 + (size_t)(kc * 32) * 2048 + jg;
    float acc[BG] = {0, 0, 0, 0};
    for (int kk4 = 0; kk4 < 32; kk4 += 4) {     // 4 wide loads = 16 k per iter
      const float4 w0 = wp4[(size_t)(kk4 + 0) * 2048];
      const float4 w1 = wp4[(size_t)(kk4 + 1) * 2048];
      const float4 w2 = wp4[(size_t)(kk4 + 2) * 2048];
      const float4 w3 = wp4[(size_t)(kk4 + 3) * 2048];
      #pragma unroll
      for (int bl = 0; bl < BG; ++bl) {
        const float4 x0 = *(const float4*)&X[bl][k0c + kk4 * 4];
        const float4 x1 = *(const float4*)&X[bl][k0c + kk4 * 4 + 4];
        const float4 x2 = *(const float4*)&X[bl][k0c + kk4 * 4 + 8];
        const float4 x3 = *(const float4*)&X[bl][k0c + kk4 * 4 + 12];
        acc[bl] += w0.x * x0.x + w0.y * x0.y + w0.z * x0.z + w0.w * x0.w
                 + w1.x * x1.x + w1.y * x1.y + w1.z * x1.z + w1.w * x1.w
                 + w2.x * x2.x + w2.y * x2.y + w2.z * x2.z + w2.w * x2.w
                 + w3.x * x3.x + w3.y * x3.y + w3.z * x3.z + w3.w * x3.w;
      }
    }
    #pragma unroll
    for (int bl = 0; bl < BG; ++bl) gacc[kc][jloc][bl] = acc[bl];
  }
  __syncthreads();

  // ---- kc-reduce + bias -> gl (256 threads: 4 bl x 64 jloc) ----
  if (tid < 256) {
    const int bl = tid >> 6, jloc = tid & 63;
    const int gi = jloc >> 4, ho = jloc & 15;
    const int jg = gi * 512 + sl * HSL + ho;
    float g = bih[jg] + bhh[jg];
    #pragma unroll
    for (int kc = 0; kc < 8; ++kc) g += gacc[kc][jloc][bl];
    gl[gi][ho][bl] = g;
  }
  __syncthreads();

  // ---- LSTM cell (64 threads: 4 bl x 16 ho) ----
  if (tid < BG * HSL) {
    const int ho = tid & 15, bl = tid >> 4;
    const int bglob = b0 + bl, hid = sl * HSL + ho;
    float i_ = sigmoidf_(gl[0][ho][bl]);
    float f_ = sigmoidf_(gl[1][ho][bl]);
    float g_ = tanhf(gl[2][ho][bl]);
    float o_ = sigmoidf_(gl[3][ho][bl]);
    float cv = cbuf[bglob * 512 + hid];          // unique owner (sl,bg)
    float cn = f_ * cv + i_ * g_;
    cbuf[bglob * 512 + hid] = cn;
    float hv = o_ * tanhf(cn);
    hbuf[((t + 1) & 1) * (B * 512) + bglob * 512 + hid] = hv;
    hl[bl][ho] = hv;
  }
  __syncthreads();

  // ---- q-partials: qpart[sl][b][d] = sum_{ho} h[b][sl*16+ho] * Wq[sl*16+ho][d] ----
  {
    float w[HSL];
    #pragma unroll
    for (int ho = 0; ho < HSL; ++ho)
      w[ho] = Wq[(size_t)(sl * HSL + ho) * 512 + tid];
    #pragma unroll
    for (int bl = 0; bl < BG; ++bl) {
      float acc = 0.f;
      #pragma unroll
      for (int ho = 0; ho < HSL; ++ho) acc += hl[bl][ho] * w[ho];
      qpart[((size_t)sl * B + b0 + bl) * 512 + tid] = acc;
    }
  }
}

// ---------------- attn (round-11 exact): pairwise rows + 1-pair prefetch ----------------
// grid 256 = (b: 32) x (ch: 8), 512 threads = 8 waves.
__global__ __launch_bounds__(512, 1)
void k_attn(const float* __restrict__ enc, const float* __restrict__ qpart,
            const int* __restrict__ ns_buf, float* __restrict__ ch_m,
            float* __restrict__ ch_l, float* __restrict__ ch_o) {
  __shared__ float q_lds[512];
  __shared__ float wm[8], wl[8];
  __shared__ float wo[8][512];
  const int b  = blockIdx.x >> 3;
  const int ch = blockIdx.x & 7;
  const int tid = threadIdx.x;
  const int lane = tid & 63;
  const int wv = tid >> 6;

  // q = sum over 32 slices
  {
    float s = 0.f;
    #pragma unroll 8
    for (int sl = 0; sl < NSL; ++sl)
      s += qpart[((size_t)sl * B + b) * 512 + tid];
    q_lds[tid] = s;
  }
  __syncthreads();

  const float4 qa  = *(const float4*)&q_lds[lane * 8];
  const float4 qb4 = *(const float4*)&q_lds[lane * 8 + 4];

  const int s0 = ch * SCHUNK;
  const int nsb = ns_buf[b];
  float m = -1e30f, l = 0.f;
  float o0=0,o1=0,o2=0,o3=0,o4=0,o5=0,o6=0,o7=0;

  const int send = min(s0 + SCHUNK, nsb);
  const size_t rowbase = (size_t)b * S;

  int r = s0 + 2 * wv;
  if (r < send) {
    bool has1 = (r + 1 < send);
    const float4* p0 = (const float4*)(enc + (rowbase + r) * 512 + lane * 8);
    const float4* p1 = (const float4*)(enc + (rowbase + (has1 ? r + 1 : r)) * 512 + lane * 8);
    float4 a0 = p0[0], a1 = p0[1];
    float4 c0 = p1[0], c1 = p1[1];
    while (true) {
      const int rn = r + 16;
      const bool hasn = (rn < send);
      float4 na0, na1, nc0, nc1;
      bool nhas1 = false;
      if (hasn) {
        nhas1 = (rn + 1 < send);
        const float4* f0 = (const float4*)(enc + (rowbase + rn) * 512 + lane * 8);
        const float4* f1 = (const float4*)(enc + (rowbase + (nhas1 ? rn + 1 : rn)) * 512 + lane * 8);
        na0 = f0[0]; na1 = f0[1]; nc0 = f1[0]; nc1 = f1[1];
      }
      float d0 = qa.x*a0.x + qa.y*a0.y + qa.z*a0.z + qa.w*a0.w
               + qb4.x*a1.x + qb4.y*a1.y + qb4.z*a1.z + qb4.w*a1.w;
      float d1 = qa.x*c0.x + qa.y*c0.y + qa.z*c0.z + qa.w*c0.w
               + qb4.x*c1.x + qb4.y*c1.y + qb4.z*c1.z + qb4.w*c1.w;
      #pragma unroll
      for (int off = 32; off > 0; off >>= 1) {
        d0 += __shfl_xor(d0, off);
        d1 += __shfl_xor(d1, off);
      }
      if (!has1) d1 = -1e30f;            // wave-uniform
      float nm = fmaxf(m, fmaxf(d0, d1));
      float sc = __expf(m - nm);
      float w0 = __expf(d0 - nm);
      float w1 = __expf(d1 - nm);        // 0 when pair's 2nd row invalid
      l = l * sc + w0 + w1;
      o0 = o0*sc + w0*a0.x + w1*c0.x; o1 = o1*sc + w0*a0.y + w1*c0.y;
      o2 = o2*sc + w0*a0.z + w1*c0.z; o3 = o3*sc + w0*a0.w + w1*c0.w;
      o4 = o4*sc + w0*a1.x + w1*c1.x; o5 = o5*sc + w0*a1.y + w1*c1.y;
      o6 = o6*sc + w0*a1.z + w1*c1.z; o7 = o7*sc + w0*a1.w + w1*c1.w;
      m = nm;
      if (!hasn) break;
      r = rn; has1 = nhas1;
      a0 = na0; a1 = na1; c0 = nc0; c1 = nc1;
    }
  }
  if (lane == 0) { wm[wv] = m; wl[wv] = l; }
  float4* wop = (float4*)&wo[wv][lane * 8];
  wop[0] = make_float4(o0, o1, o2, o3);
  wop[1] = make_float4(o4, o5, o6, o7);
  __syncthreads();

  float M = wm[0];
  #pragma unroll
  for (int w = 1; w < 8; ++w) M = fmaxf(M, wm[w]);
  float e[8]; float L = 0.f;
  #pragma unroll
  for (int w = 0; w < 8; ++w) { e[w] = __expf(wm[w] - M); L += wl[w] * e[w]; }
  if (tid == 0) { ch_m[b * NCH + ch] = M; ch_l[b * NCH + ch] = L; }
  float v = 0.f;
  #pragma unroll
  for (int w = 0; w < 8; ++w) v += wo[w][tid] * e[w];
  ch_o[((size_t)(b * NCH + ch)) * 512 + tid] = v;
}

extern "C" void kernel_launch(void* const* d_in, const int* in_sizes, int n_in,
                              void* d_out, int out_size, void* d_ws, size_t ws_size,
                              hipStream_t stream) {
  const float* enc     = (const float*)d_in[0];
  const int*   ns_raw  = (const int*)d_in[1];
  // d_in[2] = num_pred (8)
  const float* init_h  = (const float*)d_in[3];
  const float* init_c  = (const float*)d_in[4];
  const float* init_in = (const float*)d_in[5];
  const float* W_ih    = (const float*)d_in[6];
  const float* W_hh    = (const float*)d_in[7];
  const float* b_ih    = (const float*)d_in[8];
  const float* b_hh    = (const float*)d_in[9];
  const float* Wq      = (const float*)d_in[10];
  const float* score_W = (const float*)d_in[11];
  const float* score_b = (const float*)d_in[12];
  float* out = (float*)d_out;

  float* ws    = (float*)d_ws;
  float4* Wt4  = (float4*)ws;         // 256 k4 x 2048 j float4 = 2097152 floats
  float* hbuf  = ws + 2097152;        // 2*B*H = 32768 (double-buffered)
  float* cbuf  = ws + 2129920;        // 16384
  float* xin0  = ws + 2146304;        // 16384
  float* qpart = ws + 2162688;        // NSL*B*512 = 524288
  float* ch_m  = ws + 2686976;        // B*NCH = 256
  float* ch_l  = ws + 2687232;        // 256
  float* ch_o  = ws + 2687488;        // B*NCH*512 = 131072
  int*   ns    = (int*)(ws + 2818560); // 32 ints

  k_init<<<512, 256, 0, stream>>>(W_ih, W_hh, init_h, init_c, init_in, ns_raw,
                                  Wt4, hbuf, cbuf, xin0, ns);
  for (int t = 0; t < NP; ++t) {
    k_step<<<NSL * NBT, 512, 0, stream>>>(xin0, b_ih, b_hh, Wq, score_W, score_b, Wt4,
                                          ch_m, ch_l, ch_o, hbuf, cbuf, qpart, out, t);
    k_attn<<<B * NCH, 512, 0, stream>>>(enc, qpart, ns, ch_m, ch_l, ch_o);
  }
  k_step<<<NSL * NBT, 512, 0, stream>>>(xin0, b_ih, b_hh, Wq, score_W, score_b, Wt4,
                                        ch_m, ch_l, ch_o, hbuf, cbuf, qpart, out, NP);
}